// Round 14
// baseline (1060.919 us; speedup 1.0000x reference)
//
#include <hip/hip_runtime.h>

#define IN_F 4096
#define OUT_F 16384
#define MTOK 8192   // B*S

#define BM 256
#define BN 256
#define BK 64
#define NKT (IN_F / BK)   // 64 K-tiles

typedef __attribute__((ext_vector_type(4)))  int   i32x4;
typedef __attribute__((ext_vector_type(4)))  float f32x4;

__device__ __forceinline__ void gload_lds16(const void* g, void* l) {
    __builtin_amdgcn_global_load_lds(
        (const __attribute__((address_space(1))) void*)g,
        (__attribute__((address_space(3))) void*)l,
        16, 0, 0);
}

// ---------------------------------------------------------------------------
// Kernel 1: per-token absmax -> int8 quantize x, store scale
// ---------------------------------------------------------------------------
__global__ __launch_bounds__(256) void k_quant(const float* __restrict__ x,
                                               char* __restrict__ xq,
                                               float* __restrict__ xs) {
    const int m = blockIdx.x;
    const int t = threadIdx.x;
    const float* xrow = x + (size_t)m * IN_F;

    f32x4 v[4];
    float mx = 0.f;
#pragma unroll
    for (int i = 0; i < 4; ++i) {
        v[i] = *(const f32x4*)&xrow[(i * 256 + t) * 4];
        mx = fmaxf(mx, fmaxf(fmaxf(fabsf(v[i].x), fabsf(v[i].y)),
                             fmaxf(fabsf(v[i].z), fabsf(v[i].w))));
    }
#pragma unroll
    for (int off = 32; off > 0; off >>= 1)
        mx = fmaxf(mx, __shfl_xor(mx, off));

    __shared__ float wmax[4];
    const int wid = t >> 6;
    if ((t & 63) == 0) wmax[wid] = mx;
    __syncthreads();
    const float scale = fmaxf(fmaxf(fmaxf(wmax[0], wmax[1]),
                                    fmaxf(wmax[2], wmax[3])), 1e-5f);
    const float inv = 127.0f / scale;

    int* xqi = (int*)(xq + (size_t)m * IN_F);
#pragma unroll
    for (int i = 0; i < 4; ++i) {
        int q0 = (int)rintf(fminf(fmaxf(v[i].x * inv, -128.f), 127.f));
        int q1 = (int)rintf(fminf(fmaxf(v[i].y * inv, -128.f), 127.f));
        int q2 = (int)rintf(fminf(fmaxf(v[i].z * inv, -128.f), 127.f));
        int q3 = (int)rintf(fminf(fmaxf(v[i].w * inv, -128.f), 127.f));
        xqi[i * 256 + t] = (q0 & 255) | ((q1 & 255) << 8) |
                           ((q2 & 255) << 16) | (q3 << 24);
    }
    if (t == 0) xs[m] = scale;
}

// ---------------------------------------------------------------------------
// Kernel 2: ternary int32 weights -> int8 pack
// ---------------------------------------------------------------------------
__global__ __launch_bounds__(256) void k_wconv(const int* __restrict__ wt,
                                               int* __restrict__ w8) {
    const int total4 = OUT_F * IN_F / 4;
    int idx = blockIdx.x * 256 + threadIdx.x;
    const int stride = gridDim.x * 256;
    for (; idx < total4; idx += stride) {
        i32x4 w = *(const i32x4*)&wt[(size_t)idx * 4];
        w8[idx] = (w.x & 255) | ((w.y & 255) << 8) |
                  ((w.z & 255) << 16) | (w.w << 24);
    }
}

// ---------------------------------------------------------------------------
// Kernel 3: i8 GEMM — FAT-WAVE: 4 waves (1/SIMD), wave tile 128x128,
// acc = 256 AGPR, fragment REGISTER double-buffer (the overlap mechanism
// R4-R13 could never afford at 2 waves/SIMD).
//
// Body(kt):  STAGE(kt+2)->buf[(kt+2)%4]  |  vmcnt(8) (retires S(kt+1))  |
//            BAR  |  ds_read tile kt+1 -> Nxt regs  |  64 MFMA on Cur.
// The MFMA cluster (~1306 SIMD-cyc) covers next-tile ds_reads (500 cyc of
// CU LDS pipe) + stage issue: in-wave pipeline, counted lgkm by compiler
// (plain C++ ds_reads, no inline lgkm asm -> rule #18 safe).
//
// 4-buffer rotation makes WAR barrier-proven (not timing-luck): buf X is
// read by R(X) [body X-1]; wave W's M(X) [body X] waits those reads; W
// reaches BAR_{X+1} only after M(X); any wave's next write S(X+4) issues
// in body X+2, strictly after BAR_{X+1}. Write->read: each wave's VM8 in
// body X-1 retires its own S(X) before BAR_{X-1}; R(X) follows the BAR.
//
// Swizzle (R10/R12-proven, 0 conflicts): 64B rows, phys chunk =
// logical ^ ((row>>1)&3); staging permutes global SOURCE within each row's
// 64B (thread t: row r0=t>>2 (+64j), chunk (t&3)^((t>>3)&3)); frag read
// row=lane&15, phys chunk=(lane>>4)^((lane>>1)&3).
// vmcnt ledger: body VM8 (S(kt+1):8 old + S(kt+2):8 new -> retires old 8);
// body 62: VM0; body 63: none. Frag sets alternate by parity, 4-body
// unroll -> all buffer indices static (rule #20).
// ---------------------------------------------------------------------------
__global__ __launch_bounds__(256, 1) void k_gemm(
    const char*  __restrict__ Aq,     // [MTOK][IN_F] int8
    const char*  __restrict__ Bq,     // [OUT_F][IN_F] int8
    const float* __restrict__ xs,     // [MTOK]
    const float* __restrict__ wsp,    // [1]
    float*       __restrict__ C) {    // [MTOK][OUT_F]
    __shared__ __align__(16) char lds[131072];  // A: 4x16K @0; B: 4x16K @64K

    const int t    = threadIdx.x;
    const int lane = t & 63;
    const int wid  = t >> 6;          // 0..3
    const int wr   = wid >> 1;        // 0..1 (M half, 128 rows)
    const int wc   = wid & 1;         // 0..1 (N half, 128 cols)

    // XCD band mapping: grid 2048 = 32(M) x 64(N); XCD (bid&7) owns an
    // 8-wide bn band. Bijective.
    const int bid = blockIdx.x;
    const int bn  = (bid & 7) * 8 + ((bid >> 3) & 7);
    const int bm  = bid >> 6;
    const int mBase = bm * BM;
    const int nBase = bn * BN;

    // --- staging source: thread t -> row r0 = t>>2 (+64 per sweep), phys
    // chunk t&3, logical source chunk (t&3)^((t>>3)&3). Sweeps +64 rows
    // keep (row>>1)&3 (64 = 0 mod 8).
    const int r0 = t >> 2;
    const int c0 = (((t & 3) ^ ((t >> 3) & 3)) << 4);

#define STAGE(kt, bx) do {                                                     \
        const size_t ks = (size_t)(kt) * BK;                                   \
        const char* Ab = Aq + (size_t)(mBase + r0) * IN_F + ks + c0;           \
        const char* Bb = Bq + (size_t)(nBase + r0) * IN_F + ks + c0;           \
        char* dA = lds + (bx) * 16384 + wid * 1024;                            \
        char* dB = lds + 65536 + (bx) * 16384 + wid * 1024;                    \
        gload_lds16(Ab,                       dA);                             \
        gload_lds16(Ab + (size_t) 64 * IN_F,  dA + 4096);                      \
        gload_lds16(Ab + (size_t)128 * IN_F,  dA + 8192);                      \
        gload_lds16(Ab + (size_t)192 * IN_F,  dA + 12288);                     \
        gload_lds16(Bb,                       dB);                             \
        gload_lds16(Bb + (size_t) 64 * IN_F,  dB + 4096);                      \
        gload_lds16(Bb + (size_t)128 * IN_F,  dB + 8192);                      \
        gload_lds16(Bb + (size_t)192 * IN_F,  dB + 12288);                     \
    } while (0)

    // --- fragment read: row = lane&15, phys chunk = (lane>>4)^((row>>1)&3)
    const int fOff = (lane & 15) * 64 + ((((lane >> 4) ^ (lane >> 1)) & 3) << 4);

#define RD(av, bv, bx) do {                                                    \
        const char* pA = lds + (bx) * 16384 + wr * 8192;                       \
        const char* pB = lds + 65536 + (bx) * 16384 + wc * 8192;               \
        _Pragma("unroll")                                                      \
        for (int i = 0; i < 8; ++i)                                            \
            av[i] = *(const i32x4*)(pA + i * 1024 + fOff);                     \
        _Pragma("unroll")                                                      \
        for (int i = 0; i < 8; ++i)                                            \
            bv[i] = *(const i32x4*)(pB + i * 1024 + fOff);                     \
    } while (0)

#define M64(av, bv)                                                            \
    __builtin_amdgcn_s_setprio(1);                                             \
    _Pragma("unroll")                                                          \
    for (int mi = 0; mi < 8; ++mi)                                             \
        _Pragma("unroll")                                                      \
        for (int ni = 0; ni < 8; ++ni)                                         \
            acc[mi][ni] = __builtin_amdgcn_mfma_i32_16x16x64_i8(               \
                av[mi], bv[ni], acc[mi][ni], 0, 0, 0);                         \
    __builtin_amdgcn_s_setprio(0);

#define BARM()  asm volatile("s_barrier" ::: "memory")
#define VM8()   asm volatile("s_waitcnt vmcnt(8)" ::: "memory")
#define VM0()   asm volatile("s_waitcnt vmcnt(0)" ::: "memory")

#define BODY(kt, CA, CB, NA, NB, BX2, BXN) do {                                \
        if ((kt) + 2 < NKT) { STAGE((kt) + 2, BX2); VM8(); }                   \
        else if ((kt) + 1 < NKT) { VM0(); }                                    \
        if ((kt) + 1 < NKT) { BARM(); RD(NA, NB, BXN); }                       \
        M64(CA, CB);                                                           \
    } while (0)

    i32x4 acc[8][8];
#pragma unroll
    for (int i = 0; i < 8; ++i)
#pragma unroll
        for (int j = 0; j < 8; ++j)
            acc[i][j] = (i32x4){0, 0, 0, 0};

    i32x4 a0[8], b0[8], a1[8], b1[8];

    // ---- prologue: S(0)->buf0, S(1)->buf1; VM8 retires S(0); read tile 0
    STAGE(0, 0);
    STAGE(1, 1);
    VM8();
    BARM();
    RD(a0, b0, 0);

    for (int it = 0; it < NKT / 4; ++it) {
        const int k0 = it * 4;
        BODY(k0 + 0, a0, b0, a1, b1, 2, 1);
        BODY(k0 + 1, a1, b1, a0, b0, 3, 2);
        BODY(k0 + 2, a0, b0, a1, b1, 0, 3);
        BODY(k0 + 3, a1, b1, a0, b0, 1, 0);
    }

    // ---- epilogue: D row = (lane>>4)*4 + r, col = lane&15 (verified R1-R13)
    const float wsc = wsp[0] * (1.0f / 127.0f);
#pragma unroll
    for (int mi = 0; mi < 8; ++mi) {
        float rs[4];
#pragma unroll
        for (int r = 0; r < 4; ++r)
            rs[r] = xs[mBase + wr * 128 + mi * 16 + (lane >> 4) * 4 + r] * wsc;
#pragma unroll
        for (int ni = 0; ni < 8; ++ni) {
            const int col = nBase + wc * 128 + ni * 16 + (lane & 15);
#pragma unroll
            for (int r = 0; r < 4; ++r) {
                const int row = mBase + wr * 128 + mi * 16 + (lane >> 4) * 4 + r;
                C[(size_t)row * OUT_F + col] = (float)acc[mi][ni][r] * rs[r];
            }
        }
    }
}

// ---------------------------------------------------------------------------
extern "C" void kernel_launch(void* const* d_in, const int* in_sizes, int n_in,
                              void* d_out, int out_size, void* d_ws, size_t ws_size,
                              hipStream_t stream) {
    const float* x   = (const float*)d_in[0];
    const int*   wt  = (const int*)d_in[1];
    const float* wsp = (const float*)d_in[2];
    float* out = (float*)d_out;

    char*  w8 = (char*)d_ws;
    char*  xq = (char*)d_ws + (size_t)OUT_F * IN_F;
    float* xs = (float*)((char*)d_ws + (size_t)OUT_F * IN_F
                                     + (size_t)MTOK * IN_F);

    k_wconv<<<8192, 256, 0, stream>>>(wt, (int*)w8);
    k_quant<<<MTOK, 256, 0, stream>>>(x, xq, xs);

    const int grid = (MTOK / BM) * (OUT_F / BN);  // 32 * 64 = 2048
    k_gemm<<<grid, 256, 0, stream>>>(xq, w8, xs, wsp, out);
}

// Round 15
// 691.260 us; speedup vs baseline: 1.5348x; 1.5348x over previous
//
#include <hip/hip_runtime.h>

#define IN_F 4096
#define OUT_F 16384
#define MTOK 8192   // B*S

#define BM 256
#define BN 256
#define BK 64
#define NKT (IN_F / BK)   // 64 K-tiles

typedef __attribute__((ext_vector_type(4)))  int   i32x4;
typedef __attribute__((ext_vector_type(16))) int   i32x16;
typedef __attribute__((ext_vector_type(4)))  float f32x4;

__device__ __forceinline__ void gload_lds16(const void* g, void* l) {
    __builtin_amdgcn_global_load_lds(
        (const __attribute__((address_space(1))) void*)g,
        (__attribute__((address_space(3))) void*)l,
        16, 0, 0);
}

// ---------------------------------------------------------------------------
// Kernel 1: per-token absmax -> int8 quantize x, store scale
// ---------------------------------------------------------------------------
__global__ __launch_bounds__(256) void k_quant(const float* __restrict__ x,
                                               char* __restrict__ xq,
                                               float* __restrict__ xs) {
    const int m = blockIdx.x;
    const int t = threadIdx.x;
    const float* xrow = x + (size_t)m * IN_F;

    f32x4 v[4];
    float mx = 0.f;
#pragma unroll
    for (int i = 0; i < 4; ++i) {
        v[i] = *(const f32x4*)&xrow[(i * 256 + t) * 4];
        mx = fmaxf(mx, fmaxf(fmaxf(fabsf(v[i].x), fabsf(v[i].y)),
                             fmaxf(fabsf(v[i].z), fabsf(v[i].w))));
    }
#pragma unroll
    for (int off = 32; off > 0; off >>= 1)
        mx = fmaxf(mx, __shfl_xor(mx, off));

    __shared__ float wmax[4];
    const int wid = t >> 6;
    if ((t & 63) == 0) wmax[wid] = mx;
    __syncthreads();
    const float scale = fmaxf(fmaxf(fmaxf(wmax[0], wmax[1]),
                                    fmaxf(wmax[2], wmax[3])), 1e-5f);
    const float inv = 127.0f / scale;

    int* xqi = (int*)(xq + (size_t)m * IN_F);
#pragma unroll
    for (int i = 0; i < 4; ++i) {
        int q0 = (int)rintf(fminf(fmaxf(v[i].x * inv, -128.f), 127.f));
        int q1 = (int)rintf(fminf(fmaxf(v[i].y * inv, -128.f), 127.f));
        int q2 = (int)rintf(fminf(fmaxf(v[i].z * inv, -128.f), 127.f));
        int q3 = (int)rintf(fminf(fmaxf(v[i].w * inv, -128.f), 127.f));
        xqi[i * 256 + t] = (q0 & 255) | ((q1 & 255) << 8) |
                           ((q2 & 255) << 16) | (q3 << 24);
    }
    if (t == 0) xs[m] = scale;
}

// ---------------------------------------------------------------------------
// Kernel 2: ternary int32 weights -> int8 pack
// ---------------------------------------------------------------------------
__global__ __launch_bounds__(256) void k_wconv(const int* __restrict__ wt,
                                               int* __restrict__ w8) {
    const int total4 = OUT_F * IN_F / 4;
    int idx = blockIdx.x * 256 + threadIdx.x;
    const int stride = gridDim.x * 256;
    for (; idx < total4; idx += stride) {
        i32x4 w = *(const i32x4*)&wt[(size_t)idx * 4];
        w8[idx] = (w.x & 255) | ((w.y & 255) << 8) |
                  ((w.z & 255) << 16) | (w.w << 24);
    }
}

// ---------------------------------------------------------------------------
// Kernel 3: i8 GEMM — R12 skeleton (best: 486us, 50.4% MfmaUtil) with
// mfma_i32_32x32x32_i8 (4404 vs 3944 TOPS, half the MFMA instructions).
//
// R5's 32x32 failure fixed on both counts:
//  (a) swizzle: per-16-lane b128 quarter, phys chunk =
//      logical ^ ((row>>1)&3) ^ ((row>>3)&3) gives each (parity(row), base)
//      exactly 2 lanes = free 2-way (lane-verified, all quarters & kk).
//      Staging source applies the same involution:
//      c0 = (t&3) ^ ((t>>3)&3) ^ ((t>>5)&3)  (row r0 = t>>2; +64/128-row
//      sweeps preserve both XOR terms).
//  (b) dep chains: kk OUTER in each 8-MFMA cluster -> 4 independent acc
//      targets between reuses.
//
// Skeleton (R12-proven): 256x256 tile, BK=64, 8 waves 2Mx4N (wave 128x64),
// 3-buffer LDS rotation (A at x*16384, B at 49152+x*16384), spread-phase
// reads, 2 sub-phases + 2 barriers per K-tile, vmcnt(4) ledger:
// body(kt) stages kt+2 into buf (kt+2)%3 (fully consumed body(kt-1));
// VM4 at body end retires exactly stage(kt+1); tail VM0.
// Epilogue: R5's correctness-verified 32x32 C/D map (col=lane&31,
// row=(reg&3)+8*(reg>>2)+4*(lane>>5)) -> 128B store segments.
// ---------------------------------------------------------------------------
__global__ __launch_bounds__(512, 2) void k_gemm(
    const char*  __restrict__ Aq,     // [MTOK][IN_F] int8
    const char*  __restrict__ Bq,     // [OUT_F][IN_F] int8
    const float* __restrict__ xs,     // [MTOK]
    const float* __restrict__ wsp,    // [1]
    float*       __restrict__ C) {    // [MTOK][OUT_F]
    __shared__ __align__(16) char lds[98304];   // A: 0..48K, B: 48K..96K

    const int t    = threadIdx.x;
    const int lane = t & 63;
    const int wid  = t >> 6;
    const int wr   = wid >> 2;        // 0..1  (M half, 128 rows)
    const int wc   = wid & 3;         // 0..3  (N quarter, 64 cols)
    const int h    = lane >> 5;       // 32-lane half

    // XCD band mapping: grid 2048 = 32(M) x 64(N); XCD (bid&7) owns an
    // 8-wide bn band. Bijective.
    const int bid = blockIdx.x;
    const int bn  = (bid & 7) * 8 + ((bid >> 3) & 7);
    const int bm  = bid >> 6;
    const int mBase = bm * BM;
    const int nBase = bn * BN;

    // --- staging source: thread t -> row r0 = t>>2, phys chunk t&3,
    // logical source chunk = (t&3) ^ ((r0>>1)&3) ^ ((r0>>3)&3)
    //                      = (t&3) ^ ((t>>3)&3) ^ ((t>>5)&3).
    // Rows +64/+128 preserve both XOR terms (64,128 = 0 mod 16... bits 1-4
    // of row shift by multiples of 32/64 -> (r>>1)&3 and (r>>3)&3 unchanged).
    const int r0 = t >> 2;
    const int c0 = ((((t & 3) ^ ((t >> 3) & 3)) ^ ((t >> 5) & 3)) << 4);

#define STAGE(kt, bx) do {                                                     \
        const size_t ks = (size_t)(kt) * BK;                                   \
        gload_lds16(Aq + (size_t)(mBase + r0) * IN_F + ks + c0,                \
                    lds + (bx) * 16384 + wid * 1024);                          \
        gload_lds16(Aq + (size_t)(mBase + 128 + r0) * IN_F + ks + c0,          \
                    lds + (bx) * 16384 + 8192 + wid * 1024);                   \
        gload_lds16(Bq + (size_t)(nBase + r0) * IN_F + ks + c0,                \
                    lds + 49152 + (bx) * 16384 + wid * 1024);                  \
        gload_lds16(Bq + (size_t)(nBase + 128 + r0) * IN_F + ks + c0,          \
                    lds + 49152 + (bx) * 16384 + 8192 + wid * 1024);           \
    } while (0)

    // --- fragment read: row = lane&31, logical chunk = 2kk + h,
    // phys chunk = (2kk+h) ^ ((row>>1)&3) ^ ((row>>3)&3)
    const int vx = ((lane >> 1) ^ (lane >> 3)) & 3;
    int fOff[2];
#pragma unroll
    for (int kk = 0; kk < 2; ++kk)
        fOff[kk] = (lane & 31) * 64 + (((2 * kk + h) ^ vx) << 4);
    const char* ldsA = lds + wr * 8192;            // + x*16384 + mi*2048
    const char* ldsB = lds + 49152 + wc * 4096;    // + x*16384 + ni*2048

// kk OUTER: 4 independent acc targets between reuses
#define MFMA8(Af, MIB)                                                         \
    __builtin_amdgcn_s_setprio(1);                                             \
    _Pragma("unroll")                                                          \
    for (int kk = 0; kk < 2; ++kk)                                             \
        _Pragma("unroll")                                                      \
        for (int mi = 0; mi < 2; ++mi)                                         \
            _Pragma("unroll")                                                  \
            for (int ni = 0; ni < 2; ++ni)                                     \
                acc[(MIB) + mi][ni] = __builtin_amdgcn_mfma_i32_32x32x32_i8(   \
                    Af[mi][kk], b[ni][kk], acc[(MIB) + mi][ni], 0, 0, 0);      \
    __builtin_amdgcn_s_setprio(0);

#define BAR()   __builtin_amdgcn_s_barrier()
#define VM4()   asm volatile("s_waitcnt vmcnt(4)" ::: "memory")
#define VM0()   asm volatile("s_waitcnt vmcnt(0)" ::: "memory")

    i32x16 acc[4][2];
#pragma unroll
    for (int i = 0; i < 4; ++i)
#pragma unroll
        for (int j = 0; j < 2; ++j)
            acc[i][j] = (i32x16)(0);

    // ---- prologue: tile0 -> buf0, tile1 -> buf1; VM4 retires tile0 exactly
    STAGE(0, 0);
    STAGE(1, 1);
    VM4();
    BAR();

    int x = 0, x2 = 2;   // kt % 3, (kt+2) % 3
    for (int kt = 0; kt < NKT; ++kt) {
        const int xo = x * 16384;
        const bool more = (kt + 2 < NKT);
        i32x4 aLo[2][2], aHi[2][2], b[2][2];

        // ---- sub1: aLo (mi0-1) + all B; 8 MFMA
#pragma unroll
        for (int mi = 0; mi < 2; ++mi)
#pragma unroll
            for (int kk = 0; kk < 2; ++kk)
                aLo[mi][kk] = *(const i32x4*)(ldsA + xo + mi * 2048 + fOff[kk]);
#pragma unroll
        for (int ni = 0; ni < 2; ++ni)
#pragma unroll
            for (int kk = 0; kk < 2; ++kk)
                b[ni][kk] = *(const i32x4*)(ldsB + xo + ni * 2048 + fOff[kk]);
        MFMA8(aLo, 0);
        BAR();

        // ---- sub2: aHi (mi2-3) + stage(kt+2); 8 MFMA; counted drain
#pragma unroll
        for (int mi = 0; mi < 2; ++mi)
#pragma unroll
            for (int kk = 0; kk < 2; ++kk)
                aHi[mi][kk] = *(const i32x4*)(ldsA + xo + (2 + mi) * 2048 + fOff[kk]);
        if (more) STAGE(kt + 2, x2);
        MFMA8(aHi, 2);
        if (more) { VM4(); } else { VM0(); }
        BAR();

        x  = (x  == 2) ? 0 : x  + 1;
        x2 = (x2 == 2) ? 0 : x2 + 1;
    }

    // ---- epilogue: 32x32 C/D map (R5-verified): col = lane&31,
    // row = (reg&3) + 8*(reg>>2) + 4*h
    const float wsc = wsp[0] * (1.0f / 127.0f);
#pragma unroll
    for (int mi = 0; mi < 4; ++mi) {
#pragma unroll
        for (int rq = 0; rq < 4; ++rq) {
            const int rowB = mBase + wr * 128 + mi * 32 + rq * 8 + h * 4;
            const f32x4 s4 = *(const f32x4*)&xs[rowB];
#pragma unroll
            for (int ni = 0; ni < 2; ++ni) {
                const int col = nBase + wc * 64 + ni * 32 + (lane & 31);
#pragma unroll
                for (int r = 0; r < 4; ++r)
                    C[(size_t)(rowB + r) * OUT_F + col] =
                        (float)acc[mi][ni][rq * 4 + r] * (s4[r] * wsc);
            }
        }
    }
}

// ---------------------------------------------------------------------------
extern "C" void kernel_launch(void* const* d_in, const int* in_sizes, int n_in,
                              void* d_out, int out_size, void* d_ws, size_t ws_size,
                              hipStream_t stream) {
    const float* x   = (const float*)d_in[0];
    const int*   wt  = (const int*)d_in[1];
    const float* wsp = (const float*)d_in[2];
    float* out = (float*)d_out;

    char*  w8 = (char*)d_ws;
    char*  xq = (char*)d_ws + (size_t)OUT_F * IN_F;
    float* xs = (float*)((char*)d_ws + (size_t)OUT_F * IN_F
                                     + (size_t)MTOK * IN_F);

    k_wconv<<<8192, 256, 0, stream>>>(wt, (int*)w8);
    k_quant<<<MTOK, 256, 0, stream>>>(x, xq, xs);

    const int grid = (MTOK / BM) * (OUT_F / BN);  // 32 * 64 = 2048
    k_gemm<<<grid, 512, 0, stream>>>(xq, w8, xs, wsp, out);
}